// Round 2
// baseline (13800.064 us; speedup 1.0000x reference)
//
#include <hip/hip_runtime.h>
#include <math.h>

// stacked_rnn R2: persistent cooperative kernel, weights LDS-resident.
// 2-layer LSTM (B=128, T=256, I=150->160, H=1024) + FC(60), bf16 MFMA fp32-acc.
// Skewed pipeline: epoch e computes L1 step e and L2 step e-1; 1 grid barrier/epoch.

typedef __bf16 bf16;
typedef __bf16 bf16x8 __attribute__((ext_vector_type(8)));
typedef float floatx4 __attribute__((ext_vector_type(4)));

#define B_   128
#define T_   256
#define H_   1024
#define I_   150
#define KX_  160
#define C_   60
#define K1LDS 1280   // layer-1 LDS row width (150+pad | 1024 | pad) in elems
#define K2LDS 2048   // layer-2 LDS row width

__device__ __forceinline__ float sigmoidf_(float x) { return 1.f / (1.f + expf(-x)); }

// custom grid barrier: monotone counter, agent-scope release/acquire
__device__ __forceinline__ void grid_bar(unsigned* cnt, unsigned target) {
    __syncthreads();                      // all block threads' stores complete (vmcnt0)
    if (threadIdx.x == 0) {
        __hip_atomic_fetch_add(cnt, 1u, __ATOMIC_RELEASE, __HIP_MEMORY_SCOPE_AGENT);
        while (__hip_atomic_load(cnt, __ATOMIC_ACQUIRE, __HIP_MEMORY_SCOPE_AGENT) < target)
            __builtin_amdgcn_s_sleep(1);
    }
    __syncthreads();
}

// ---------------- conversion / init kernel ----------------
__global__ __launch_bounds__(256)
void convert_all(const float* __restrict__ x,
                 const float* __restrict__ h1in, const float* __restrict__ h2in,
                 bf16* __restrict__ xb, bf16* __restrict__ h1b0, bf16* __restrict__ h2b0,
                 unsigned* __restrict__ barcnt)
{
    const size_t nXB = (size_t)T_ * B_ * KX_;   // 5242880
    const size_t nHC = (size_t)B_ * H_;         // 131072
    size_t idx = (size_t)blockIdx.x * 256 + threadIdx.x;

    if (idx < nXB) {                            // x [B][T][150] -> xb [T][B][160]
        size_t t = idx / (B_ * KX_);
        size_t r = idx - t * (B_ * KX_);
        size_t b = r / KX_, k = r - b * KX_;
        xb[idx] = (k < I_) ? (bf16)x[(b * T_ + t) * I_ + k] : (bf16)0.f;
        return;
    }
    idx -= nXB;
    if (idx < nHC) { h1b0[idx] = (bf16)h1in[idx]; return; }
    idx -= nHC;
    if (idx < nHC) { h2b0[idx] = (bf16)h2in[idx]; return; }
    idx -= nHC;
    if (idx == 0) *barcnt = 0u;
}

// ---------------- persistent LSTM kernel ----------------
// NCOLS = gate-columns per block (32 -> 256 blocks/128KiB LDS; 16 -> 512 blocks/64KiB).
// Block: layer = (bid>>3)&1 (XCD-interleaved), slice = (bid&7)|((bid>>4)<<3),
//        owns h-cols [slice*NHC, slice*NHC+NHC). LDS row r = g*NHC + j (gate g, col j).
// 4 waves = 4 M-groups of 32 batch rows; per wave: 2 M-tiles x NT N-tiles, full K.
template<int NCOLS>
__global__ __launch_bounds__(256, 2)
void rnn_persistent(const bf16* __restrict__ xb,
                    bf16* __restrict__ h1b0, bf16* __restrict__ h1b1,
                    bf16* __restrict__ h2b0, bf16* __restrict__ h2b1,
                    const float* __restrict__ c1in, const float* __restrict__ c2in,
                    const float* __restrict__ Wih1, const float* __restrict__ Whh1,
                    const float* __restrict__ bih1, const float* __restrict__ bhh1,
                    const float* __restrict__ Wih2, const float* __restrict__ Whh2,
                    const float* __restrict__ bih2, const float* __restrict__ bhh2,
                    const float* __restrict__ Wfc, const float* __restrict__ bfc,
                    float* __restrict__ out, unsigned* __restrict__ barcnt, int nblk)
{
    constexpr int NHC = NCOLS / 4;      // h-cols per block
    constexpr int NT  = NCOLS / 16;     // N-tiles (2 or 1)
    extern __shared__ bf16 lds[];

    const int tid   = threadIdx.x;
    const int bid   = blockIdx.x;
    const int layer = (bid >> 3) & 1;
    const int slice = (bid & 7) | ((bid >> 4) << 3);
    const int n0h   = slice * NHC;
    const int KLDS  = layer ? K2LDS : K1LDS;

    // ---- stage weights fp32->bf16 into swizzled LDS (once) ----
    {
        const int cpr = KLDS >> 3;              // 16B chunks per row
        const int total = NCOLS * cpr;
        for (int ci = tid; ci < total; ci += 256) {
            int r = ci / cpr, c = ci - r * cpr;
            int g = r / NHC, j = r - g * NHC;
            int grow = (g << 10) + n0h + j;
            int k0 = c << 3;
            float v[8];
#pragma unroll
            for (int u = 0; u < 8; ++u) {
                int k = k0 + u;
                if (layer == 0)
                    v[u] = (k < I_) ? Wih1[(size_t)grow * I_ + k]
                         : (k < KX_) ? 0.f
                         : (k < KX_ + H_) ? Whh1[(size_t)grow * H_ + (k - KX_)] : 0.f;
                else
                    v[u] = (k < H_) ? Wih2[(size_t)grow * H_ + k]
                                    : Whh2[(size_t)grow * H_ + (k - H_)];
            }
            int cs = (c & ~15) | ((c ^ r) & 15);      // XOR swizzle within 16-chunk group
            bf16* dst = lds + (size_t)r * KLDS + (cs << 3);
#pragma unroll
            for (int u = 0; u < 8; ++u) dst[u] = (bf16)v[u];
        }
    }
    __syncthreads();

    const int lane = tid & 63;
    const int wv   = tid >> 6;          // M-group (32 rows)
    const int jj   = lane & (NHC - 1);  // this lane's h-col offset
    const int quad = lane >> 4;

    // per-lane gate biases for h-col jj
    float4 bias;
    {
        const float* bi = layer ? bih2 : bih1;
        const float* bh = layer ? bhh2 : bhh1;
        int col = n0h + jj;
        bias.x = bi[col] + bh[col];
        bias.y = bi[col + H_] + bh[col + H_];
        bias.z = bi[col + 2 * H_] + bh[col + 2 * H_];
        bias.w = bi[col + 3 * H_] + bh[col + 3 * H_];
    }

    // c-state in registers: fixed (row,hcol) -> (lane,slot) ownership
    float creg[4];
    {
        const float* cin = layer ? c2in : c1in;
        if constexpr (NCOLS == 32) {
            int dup = (lane >> 3) & 1;
#pragma unroll
            for (int t = 0; t < 2; ++t)
#pragma unroll
                for (int rp = 0; rp < 2; ++rp) {
                    int r = rp * 2 + dup;
                    int row = wv * 32 + t * 16 + quad * 4 + r;
                    creg[t * 2 + rp] = cin[(size_t)row * H_ + n0h + jj];
                }
        } else {
            int r = (lane >> 2) & 3;
#pragma unroll
            for (int t = 0; t < 2; ++t) {
                int row = wv * 32 + t * 16 + quad * 4 + r;
                creg[t] = cin[(size_t)row * H_ + n0h + jj];
            }
        }
    }

    floatx4 acc[2][NT];

    // K-segment: A row-major [128][ldA] bf16, nks k-steps of 32, LDS k-base ksBase*32
    auto seg = [&](const bf16* A, int ldA, int nks, int ksBase) {
        const int arow = wv * 32 + (lane & 15);
        const bf16* a0 = A + (size_t)arow * ldA + quad * 8;
        const bf16* a1 = a0 + 16 * ldA;
#pragma unroll 4
        for (int ks = 0; ks < nks; ++ks) {
            bf16x8 af0 = *(const bf16x8*)(a0 + ks * 32);
            bf16x8 af1 = *(const bf16x8*)(a1 + ks * 32);
            int c = (ksBase + ks) * 4 + quad;
#pragma unroll
            for (int t = 0; t < NT; ++t) {
                int r = t * 16 + (lane & 15);
                int cs = (c & ~15) | ((c ^ r) & 15);
                bf16x8 bfr = *(const bf16x8*)(lds + (size_t)r * KLDS + (cs << 3));
                acc[0][t] = __builtin_amdgcn_mfma_f32_16x16x32_bf16(af0, bfr, acc[0][t], 0, 0, 0);
                acc[1][t] = __builtin_amdgcn_mfma_f32_16x16x32_bf16(af1, bfr, acc[1][t], 0, 0, 0);
            }
        }
    };

    for (int e = 0; e <= T_; ++e) {
        const bool active = layer == 0 ? (e < T_) : (e >= 1);
        if (active) {
#pragma unroll
            for (int t = 0; t < 2; ++t)
#pragma unroll
                for (int u = 0; u < NT; ++u) acc[t][u] = (floatx4){0.f, 0.f, 0.f, 0.f};

            const bf16* h1r = (e & 1) ? h1b1 : h1b0;         // h1^(e)
            if (layer == 0) {
                const bf16* xt = xb + (size_t)e * B_ * KX_;
                seg(xt, KX_, 5, 0);
                seg(h1r, H_, 32, 5);
            } else {
                const bf16* h2r = (e & 1) ? h2b0 : h2b1;     // h2^(e-1)
                seg(h1r, H_, 32, 0);
                seg(h2r, H_, 32, 32);
            }
            bf16* hw = (layer == 0) ? ((e & 1) ? h1b0 : h1b1)   // h1^(e+1)
                                    : ((e & 1) ? h2b1 : h2b0);  // h2^(e)

            // epilogue: shfl-gather i,f,g,o per (row,hcol), update creg, store h
            const int base = lane & 48;
#pragma unroll
            for (int t = 0; t < 2; ++t) {
#pragma unroll
                for (int r = 0; r < 4; ++r) {
                    float vi, vf, vg, vo;
                    if constexpr (NCOLS == 32) {
                        vi = __shfl(acc[t][0][r], base + jj, 64);
                        vf = __shfl(acc[t][0][r], base + 8 + jj, 64);
                        vg = __shfl(acc[t][1][r], base + jj, 64);
                        vo = __shfl(acc[t][1][r], base + 8 + jj, 64);
                    } else {
                        vi = __shfl(acc[t][0][r], base + jj, 64);
                        vf = __shfl(acc[t][0][r], base + 4 + jj, 64);
                        vg = __shfl(acc[t][0][r], base + 8 + jj, 64);
                        vo = __shfl(acc[t][0][r], base + 12 + jj, 64);
                    }
                    bool cond; int slot;
                    if constexpr (NCOLS == 32) {
                        cond = (((lane >> 3) & 1) == (r & 1));
                        slot = t * 2 + (r >> 1);
                    } else {
                        cond = (((lane >> 2) & 3) == r);
                        slot = t;
                    }
                    if (cond) {
                        float cv = creg[slot];
                        float cn = sigmoidf_(vf + bias.y) * cv
                                 + sigmoidf_(vi + bias.x) * tanhf(vg + bias.z);
                        creg[slot] = cn;
                        float hn = sigmoidf_(vo + bias.w) * tanhf(cn);
                        int row = wv * 32 + t * 16 + quad * 4 + r;
                        hw[(size_t)row * H_ + n0h + jj] = (bf16)hn;
                    }
                }
            }
        }
        grid_bar(barcnt, (unsigned)((e + 1) * nblk));
    }

    // ---- fused FC: out[b][c] = h2^(256) @ Wfc^T + bfc ; h2^(256) is in h2b0 ----
    if (bid < B_) {
        const bf16* h2f = h2b0;
        for (int c = wv; c < C_; c += 4) {
            float a = 0.f;
            for (int k = lane; k < H_; k += 64)
                a += (float)h2f[(size_t)bid * H_ + k] * Wfc[(size_t)c * H_ + k];
#pragma unroll
            for (int off = 32; off; off >>= 1) a += __shfl_down(a, off, 64);
            if (lane == 0) out[bid * C_ + c] = a + bfc[c];
        }
    }
}

extern "C" void kernel_launch(void* const* d_in, const int* in_sizes, int n_in,
                              void* d_out, int out_size, void* d_ws, size_t ws_size,
                              hipStream_t stream)
{
    const float* x    = (const float*)d_in[0];
    const float* h1in = (const float*)d_in[1];
    const float* c1in = (const float*)d_in[2];
    const float* h2in = (const float*)d_in[3];
    const float* c2in = (const float*)d_in[4];
    const float* Wih1 = (const float*)d_in[5];
    const float* Whh1 = (const float*)d_in[6];
    const float* bih1 = (const float*)d_in[7];
    const float* bhh1 = (const float*)d_in[8];
    const float* Wih2 = (const float*)d_in[9];
    const float* Whh2 = (const float*)d_in[10];
    const float* bih2 = (const float*)d_in[11];
    const float* bhh2 = (const float*)d_in[12];
    const float* Wfc  = (const float*)d_in[13];
    const float* bfc  = (const float*)d_in[14];
    float* out = (float*)d_out;

    // ws carve (~11.5 MB)
    char* p = (char*)d_ws;
    bf16* xb = (bf16*)p;    p += (size_t)T_ * B_ * KX_ * 2;
    bf16* h1b0 = (bf16*)p;  p += (size_t)B_ * H_ * 2;
    bf16* h1b1 = (bf16*)p;  p += (size_t)B_ * H_ * 2;
    bf16* h2b0 = (bf16*)p;  p += (size_t)B_ * H_ * 2;
    bf16* h2b1 = (bf16*)p;  p += (size_t)B_ * H_ * 2;
    unsigned* barcnt = (unsigned*)p;

    const size_t citems = (size_t)T_ * B_ * KX_ + 2 * (size_t)B_ * H_ + 1;
    convert_all<<<(int)((citems + 255) / 256), 256, 0, stream>>>(
        x, h1in, h2in, xb, h1b0, h2b0, barcnt);

    int nblk32 = 256, nblk16 = 512;
    void* args32[] = { &xb, &h1b0, &h1b1, &h2b0, &h2b1, (void*)&c1in, (void*)&c2in,
                       (void*)&Wih1, (void*)&Whh1, (void*)&bih1, (void*)&bhh1,
                       (void*)&Wih2, (void*)&Whh2, (void*)&bih2, (void*)&bhh2,
                       (void*)&Wfc, (void*)&bfc, &out, &barcnt, &nblk32 };
    void* args16[] = { &xb, &h1b0, &h1b1, &h2b0, &h2b1, (void*)&c1in, (void*)&c2in,
                       (void*)&Wih1, (void*)&Whh1, (void*)&bih1, (void*)&bhh1,
                       (void*)&Wih2, (void*)&Whh2, (void*)&bih2, (void*)&bhh2,
                       (void*)&Wfc, (void*)&bfc, &out, &barcnt, &nblk16 };

    // primary: 256 blocks x 32 cols, 128 KiB dynamic LDS (needs >64KB support)
    (void)hipFuncSetAttribute((const void*)rnn_persistent<32>,
                              hipFuncAttributeMaxDynamicSharedMemorySize, 131072);
    hipError_t err = hipLaunchCooperativeKernel((const void*)rnn_persistent<32>,
                                                dim3(256), dim3(256), args32,
                                                131072u, stream);
    if (err != hipSuccess) {
        (void)hipGetLastError();   // clear; fall back to 64 KiB variant
        (void)hipLaunchCooperativeKernel((const void*)rnn_persistent<16>,
                                         dim3(512), dim3(256), args16,
                                         65536u, stream);
    }
}

// Round 3
// 8583.782 us; speedup vs baseline: 1.6077x; 1.6077x over previous
//
#include <hip/hip_runtime.h>
#include <math.h>

// stacked_rnn R3: persistent cooperative kernel, weights LDS-resident,
// FENCE-FREE sync: relaxed agent atomics for h-exchange + flags; one acquire
// fence per epoch (consumer side only). R2's 53us/epoch barrier was a
// buffer_inv-per-poll + wbl2-per-arrival storm.

typedef __bf16 bf16;
typedef __bf16 bf16x8 __attribute__((ext_vector_type(8)));
typedef float floatx4 __attribute__((ext_vector_type(4)));
typedef unsigned long long ull;

#define B_   128
#define T_   256
#define H_   1024
#define I_   150
#define KX_  160
#define C_   60
#define K1LDS 1280   // layer-1 LDS row width in elems
#define K2LDS 2048   // layer-2 LDS row width
#define NCTR 8       // arrival counters (separate cache lines)
#define CSTRIDE 64   // uints between counters (256B)

__device__ __forceinline__ float sigmoidf_(float x) { return 1.f / (1.f + expf(-x)); }

// ---------------- conversion / init kernel ----------------
__global__ __launch_bounds__(256)
void convert_all(const float* __restrict__ x,
                 const float* __restrict__ h1in, const float* __restrict__ h2in,
                 bf16* __restrict__ xb, bf16* __restrict__ h1b0, bf16* __restrict__ h2b0,
                 unsigned* __restrict__ cnt8)
{
    const size_t nXB = (size_t)T_ * B_ * KX_;   // 5242880
    const size_t nHC = (size_t)B_ * H_;         // 131072
    size_t idx = (size_t)blockIdx.x * 256 + threadIdx.x;

    if (idx < nXB) {                            // x [B][T][150] -> xb [T][B][160]
        size_t t = idx / (B_ * KX_);
        size_t r = idx - t * (B_ * KX_);
        size_t b = r / KX_, k = r - b * KX_;
        xb[idx] = (k < I_) ? (bf16)x[(b * T_ + t) * I_ + k] : (bf16)0.f;
        return;
    }
    idx -= nXB;
    if (idx < nHC) { h1b0[idx] = (bf16)h1in[idx]; return; }
    idx -= nHC;
    if (idx < nHC) { h2b0[idx] = (bf16)h2in[idx]; return; }
    idx -= nHC;
    if (idx < NCTR * CSTRIDE) cnt8[idx] = 0u;
}

// ---------------- persistent LSTM kernel ----------------
// NCOLS=32 -> 256 blocks/128KiB LDS; NCOLS=16 -> 512 blocks/64KiB LDS.
// layer = (bid>>3)&1 (XCD-interleaved), slice = (bid&7)|((bid>>4)<<3).
template<int NCOLS>
__global__ __launch_bounds__(256, 2)
void rnn_persistent(const bf16* __restrict__ xb,
                    bf16* __restrict__ h1b0, bf16* __restrict__ h1b1,
                    bf16* __restrict__ h2b0, bf16* __restrict__ h2b1,
                    const float* __restrict__ c1in, const float* __restrict__ c2in,
                    const float* __restrict__ Wih1, const float* __restrict__ Whh1,
                    const float* __restrict__ bih1, const float* __restrict__ bhh1,
                    const float* __restrict__ Wih2, const float* __restrict__ Whh2,
                    const float* __restrict__ bih2, const float* __restrict__ bhh2,
                    const float* __restrict__ Wfc, const float* __restrict__ bfc,
                    float* __restrict__ out, unsigned* __restrict__ cnt8, int tgt_per)
{
    constexpr int NHC = NCOLS / 4;      // h-cols per block
    constexpr int NT  = NCOLS / 16;     // N-tiles (2 or 1)
    constexpr int GPR = NHC / 4;        // 8B col-groups per row (2 or 1)
    extern __shared__ bf16 lds[];
    __shared__ __align__(16) bf16 hst[4][32][NHC];   // epilogue staging

    const int tid   = threadIdx.x;
    const int bid   = blockIdx.x;
    const int layer = (bid >> 3) & 1;
    const int slice = (bid & 7) | ((bid >> 4) << 3);
    const int n0h   = slice * NHC;
    const int KLDS  = layer ? K2LDS : K1LDS;

    // ---- stage weights fp32->bf16 into swizzled LDS (once) ----
    {
        const int cpr = KLDS >> 3;              // 16B chunks per row
        const int total = NCOLS * cpr;
        for (int ci = tid; ci < total; ci += 256) {
            int r = ci / cpr, c = ci - r * cpr;
            int g = r / NHC, j = r - g * NHC;
            int grow = (g << 10) + n0h + j;
            int k0 = c << 3;
            float v[8];
#pragma unroll
            for (int u = 0; u < 8; ++u) {
                int k = k0 + u;
                if (layer == 0)
                    v[u] = (k < I_) ? Wih1[(size_t)grow * I_ + k]
                         : (k < KX_) ? 0.f
                         : (k < KX_ + H_) ? Whh1[(size_t)grow * H_ + (k - KX_)] : 0.f;
                else
                    v[u] = (k < H_) ? Wih2[(size_t)grow * H_ + k]
                                    : Whh2[(size_t)grow * H_ + (k - H_)];
            }
            int cs = (c & ~15) | ((c ^ r) & 15);      // XOR swizzle
            bf16* dst = lds + (size_t)r * KLDS + (cs << 3);
#pragma unroll
            for (int u = 0; u < 8; ++u) dst[u] = (bf16)v[u];
        }
    }
    __syncthreads();

    const int lane = tid & 63;
    const int wv   = tid >> 6;
    const int jj   = lane & (NHC - 1);
    const int quad = lane >> 4;

    float4 bias;
    {
        const float* bi = layer ? bih2 : bih1;
        const float* bh = layer ? bhh2 : bhh1;
        int col = n0h + jj;
        bias.x = bi[col] + bh[col];
        bias.y = bi[col + H_] + bh[col + H_];
        bias.z = bi[col + 2 * H_] + bh[col + 2 * H_];
        bias.w = bi[col + 3 * H_] + bh[col + 3 * H_];
    }

    float creg[4];
    {
        const float* cin = layer ? c2in : c1in;
        if constexpr (NCOLS == 32) {
            int dup = (lane >> 3) & 1;
#pragma unroll
            for (int t = 0; t < 2; ++t)
#pragma unroll
                for (int rp = 0; rp < 2; ++rp) {
                    int r = rp * 2 + dup;
                    int row = wv * 32 + t * 16 + quad * 4 + r;
                    creg[t * 2 + rp] = cin[(size_t)row * H_ + n0h + jj];
                }
        } else {
            int r = (lane >> 2) & 3;
#pragma unroll
            for (int t = 0; t < 2; ++t) {
                int row = wv * 32 + t * 16 + quad * 4 + r;
                creg[t] = cin[(size_t)row * H_ + n0h + jj];
            }
        }
    }

    floatx4 acc[2][NT];

    auto seg = [&](const bf16* A, int ldA, int nks, int ksBase) {
        const int arow = wv * 32 + (lane & 15);
        const bf16* a0 = A + (size_t)arow * ldA + quad * 8;
        const bf16* a1 = a0 + 16 * ldA;
#pragma unroll 4
        for (int ks = 0; ks < nks; ++ks) {
            bf16x8 af0 = *(const bf16x8*)(a0 + ks * 32);
            bf16x8 af1 = *(const bf16x8*)(a1 + ks * 32);
            int c = (ksBase + ks) * 4 + quad;
#pragma unroll
            for (int t = 0; t < NT; ++t) {
                int r = t * 16 + (lane & 15);
                int cs = (c & ~15) | ((c ^ r) & 15);
                bf16x8 bfr = *(const bf16x8*)(lds + (size_t)r * KLDS + (cs << 3));
                acc[0][t] = __builtin_amdgcn_mfma_f32_16x16x32_bf16(af0, bfr, acc[0][t], 0, 0, 0);
                acc[1][t] = __builtin_amdgcn_mfma_f32_16x16x32_bf16(af1, bfr, acc[1][t], 0, 0, 0);
            }
        }
    };

    for (int e = 0; e <= T_; ++e) {
        const bool active = layer == 0 ? (e < T_) : (e >= 1);
        if (active) {
#pragma unroll
            for (int t = 0; t < 2; ++t)
#pragma unroll
                for (int u = 0; u < NT; ++u) acc[t][u] = (floatx4){0.f, 0.f, 0.f, 0.f};

            const bf16* h1r = (e & 1) ? h1b1 : h1b0;         // h1^(e)
            if (layer == 0) {
                const bf16* xt = xb + (size_t)e * B_ * KX_;
                seg(xt, KX_, 5, 0);
                seg(h1r, H_, 32, 5);
            } else {
                const bf16* h2r = (e & 1) ? h2b0 : h2b1;     // h2^(e-1)
                seg(h1r, H_, 32, 0);
                seg(h2r, H_, 32, 32);
            }
            bf16* hw = (layer == 0) ? ((e & 1) ? h1b0 : h1b1)   // h1^(e+1)
                                    : ((e & 1) ? h2b1 : h2b0);  // h2^(e)

            // epilogue: shfl-gather gates, update creg, stage h to LDS
            const int base = lane & 48;
#pragma unroll
            for (int t = 0; t < 2; ++t) {
#pragma unroll
                for (int r = 0; r < 4; ++r) {
                    float vi, vf, vg, vo;
                    if constexpr (NCOLS == 32) {
                        vi = __shfl(acc[t][0][r], base + jj, 64);
                        vf = __shfl(acc[t][0][r], base + 8 + jj, 64);
                        vg = __shfl(acc[t][1][r], base + jj, 64);
                        vo = __shfl(acc[t][1][r], base + 8 + jj, 64);
                    } else {
                        vi = __shfl(acc[t][0][r], base + jj, 64);
                        vf = __shfl(acc[t][0][r], base + 4 + jj, 64);
                        vg = __shfl(acc[t][0][r], base + 8 + jj, 64);
                        vo = __shfl(acc[t][0][r], base + 12 + jj, 64);
                    }
                    bool cond; int slot;
                    if constexpr (NCOLS == 32) {
                        cond = (((lane >> 3) & 1) == (r & 1));
                        slot = t * 2 + (r >> 1);
                    } else {
                        cond = (((lane >> 2) & 3) == r);
                        slot = t;
                    }
                    if (cond) {
                        float cv = creg[slot];
                        float cn = sigmoidf_(vf + bias.y) * cv
                                 + sigmoidf_(vi + bias.x) * tanhf(vg + bias.z);
                        creg[slot] = cn;
                        float hn = sigmoidf_(vo + bias.w) * tanhf(cn);
                        hst[wv][t * 16 + quad * 4 + r][jj] = (bf16)hn;
                    }
                }
            }
            __syncthreads();
            // vectorized 8B relaxed-agent atomic stores (write-through, no fence)
            if (lane < 32 * GPR) {
                int row_l = lane / GPR, cg = lane - row_l * GPR;
                ull v = *(const ull*)&hst[wv][row_l][cg * 4];
                __hip_atomic_store((ull*)(hw + (size_t)(wv * 32 + row_l) * H_ + n0h + cg * 4),
                                   v, __ATOMIC_RELAXED, __HIP_MEMORY_SCOPE_AGENT);
            }
        }

        // ---- arrival: drain vmem per wave, then one relaxed add per block ----
        asm volatile("s_waitcnt vmcnt(0)" ::: "memory");
        __syncthreads();
        if (tid == 0)
            __hip_atomic_fetch_add(cnt8 + (bid & 7) * CSTRIDE, 1u,
                                   __ATOMIC_RELAXED, __HIP_MEMORY_SCOPE_AGENT);
        // ---- wait: wave 0 spins relaxed on 8 padded counters ----
        const unsigned tgt = (unsigned)((e + 1) * tgt_per);
        if (tid < 64) {
            const unsigned* cp = cnt8 + (tid & 7) * CSTRIDE;
            while (__hip_atomic_load(cp, __ATOMIC_RELAXED, __HIP_MEMORY_SCOPE_AGENT) < tgt)
                __builtin_amdgcn_s_sleep(2);
        }
        __syncthreads();
        // exactly one acquire (L1+L2 inv) per wave per epoch
        __builtin_amdgcn_fence(__ATOMIC_ACQUIRE, "agent");
    }

    // ---- fused FC: out = h2^(256) @ Wfc^T + bfc ; h2^(256) is in h2b0 ----
    if (bid < B_) {
        const bf16* h2f = h2b0;
        for (int c = wv; c < C_; c += 4) {
            float a = 0.f;
            for (int k = lane; k < H_; k += 64)
                a += (float)h2f[(size_t)bid * H_ + k] * Wfc[(size_t)c * H_ + k];
#pragma unroll
            for (int off = 32; off; off >>= 1) a += __shfl_down(a, off, 64);
            if (lane == 0) out[bid * C_ + c] = a + bfc[c];
        }
    }
}

extern "C" void kernel_launch(void* const* d_in, const int* in_sizes, int n_in,
                              void* d_out, int out_size, void* d_ws, size_t ws_size,
                              hipStream_t stream)
{
    const float* x    = (const float*)d_in[0];
    const float* h1in = (const float*)d_in[1];
    const float* c1in = (const float*)d_in[2];
    const float* h2in = (const float*)d_in[3];
    const float* c2in = (const float*)d_in[4];
    const float* Wih1 = (const float*)d_in[5];
    const float* Whh1 = (const float*)d_in[6];
    const float* bih1 = (const float*)d_in[7];
    const float* bhh1 = (const float*)d_in[8];
    const float* Wih2 = (const float*)d_in[9];
    const float* Whh2 = (const float*)d_in[10];
    const float* bih2 = (const float*)d_in[11];
    const float* bhh2 = (const float*)d_in[12];
    const float* Wfc  = (const float*)d_in[13];
    const float* bfc  = (const float*)d_in[14];
    float* out = (float*)d_out;

    // ws carve (~11.5 MB)
    char* p = (char*)d_ws;
    bf16* xb = (bf16*)p;    p += (size_t)T_ * B_ * KX_ * 2;
    bf16* h1b0 = (bf16*)p;  p += (size_t)B_ * H_ * 2;
    bf16* h1b1 = (bf16*)p;  p += (size_t)B_ * H_ * 2;
    bf16* h2b0 = (bf16*)p;  p += (size_t)B_ * H_ * 2;
    bf16* h2b1 = (bf16*)p;  p += (size_t)B_ * H_ * 2;
    unsigned* cnt8 = (unsigned*)p;      // 8 counters x 256B

    const size_t citems = (size_t)T_ * B_ * KX_ + 2 * (size_t)B_ * H_ + NCTR * CSTRIDE;
    convert_all<<<(int)((citems + 255) / 256), 256, 0, stream>>>(
        x, h1in, h2in, xb, h1b0, h2b0, cnt8);

    int tgt32 = 256 / NCTR, tgt16 = 512 / NCTR;
    void* args32[] = { &xb, &h1b0, &h1b1, &h2b0, &h2b1, (void*)&c1in, (void*)&c2in,
                       (void*)&Wih1, (void*)&Whh1, (void*)&bih1, (void*)&bhh1,
                       (void*)&Wih2, (void*)&Whh2, (void*)&bih2, (void*)&bhh2,
                       (void*)&Wfc, (void*)&bfc, &out, &cnt8, &tgt32 };
    void* args16[] = { &xb, &h1b0, &h1b1, &h2b0, &h2b1, (void*)&c1in, (void*)&c2in,
                       (void*)&Wih1, (void*)&Whh1, (void*)&bih1, (void*)&bhh1,
                       (void*)&Wih2, (void*)&Whh2, (void*)&bih2, (void*)&bhh2,
                       (void*)&Wfc, (void*)&bfc, &out, &cnt8, &tgt16 };

    (void)hipFuncSetAttribute((const void*)rnn_persistent<32>,
                              hipFuncAttributeMaxDynamicSharedMemorySize, 131072);
    hipError_t err = hipLaunchCooperativeKernel((const void*)rnn_persistent<32>,
                                                dim3(256), dim3(256), args32,
                                                131072u, stream);
    if (err != hipSuccess) {
        (void)hipGetLastError();
        (void)hipFuncSetAttribute((const void*)rnn_persistent<16>,
                                  hipFuncAttributeMaxDynamicSharedMemorySize, 65536);
        (void)hipLaunchCooperativeKernel((const void*)rnn_persistent<16>,
                                         dim3(512), dim3(256), args16,
                                         65536u, stream);
    }
}

// Round 4
// 8437.783 us; speedup vs baseline: 1.6355x; 1.0173x over previous
//
#include <hip/hip_runtime.h>
#include <math.h>

// stacked_rnn R4: persistent cooperative kernel, weights LDS-resident.
// Sync = two-level contention-free barrier: per-XCD arrival counters (RMW-only
// lines) -> master block aggregates -> single broadcast flag line (read-only
// for 255 pollers). R3's 33us/epoch was read-vs-RMW contention on shared lines.

typedef __bf16 bf16;
typedef __bf16 bf16x8 __attribute__((ext_vector_type(8)));
typedef float floatx4 __attribute__((ext_vector_type(4)));
typedef unsigned long long ull;

#define B_   128
#define T_   256
#define H_   1024
#define I_   150
#define KX_  160
#define C_   60
#define K1LDS 1280   // layer-1 LDS row width in elems
#define K2LDS 2048   // layer-2 LDS row width
#define NLINES 16    // zeroed counter lines
#define CSTRIDE 64   // uints between lines (256B)

__device__ __forceinline__ float sigmoidf_(float x) { return 1.f / (1.f + expf(-x)); }

// ---------------- conversion / init kernel ----------------
__global__ __launch_bounds__(256)
void convert_all(const float* __restrict__ x,
                 const float* __restrict__ h1in, const float* __restrict__ h2in,
                 bf16* __restrict__ xb, bf16* __restrict__ h1b0, bf16* __restrict__ h2b0,
                 unsigned* __restrict__ cnt)
{
    const size_t nXB = (size_t)T_ * B_ * KX_;   // 5242880
    const size_t nHC = (size_t)B_ * H_;         // 131072
    size_t idx = (size_t)blockIdx.x * 256 + threadIdx.x;

    if (idx < nXB) {                            // x [B][T][150] -> xb [T][B][160]
        size_t t = idx / (B_ * KX_);
        size_t r = idx - t * (B_ * KX_);
        size_t b = r / KX_, k = r - b * KX_;
        xb[idx] = (k < I_) ? (bf16)x[(b * T_ + t) * I_ + k] : (bf16)0.f;
        return;
    }
    idx -= nXB;
    if (idx < nHC) { h1b0[idx] = (bf16)h1in[idx]; return; }
    idx -= nHC;
    if (idx < nHC) { h2b0[idx] = (bf16)h2in[idx]; return; }
    idx -= nHC;
    if (idx < NLINES * CSTRIDE) cnt[idx] = 0u;
}

// ---------------- persistent LSTM kernel ----------------
// NCOLS=32 -> 256 blocks/128KiB LDS; NCOLS=16 -> 512 blocks/64KiB LDS.
// layer = (bid>>3)&1 (XCD-interleaved), slice = (bid&7)|((bid>>4)<<3).
// cnt lines 0..7: per-(bid&7) arrival counters. line 8: epoch broadcast flag.
template<int NCOLS>
__global__ __launch_bounds__(256, 2)
void rnn_persistent(const bf16* __restrict__ xb,
                    bf16* __restrict__ h1b0, bf16* __restrict__ h1b1,
                    bf16* __restrict__ h2b0, bf16* __restrict__ h2b1,
                    const float* __restrict__ c1in, const float* __restrict__ c2in,
                    const float* __restrict__ Wih1, const float* __restrict__ Whh1,
                    const float* __restrict__ bih1, const float* __restrict__ bhh1,
                    const float* __restrict__ Wih2, const float* __restrict__ Whh2,
                    const float* __restrict__ bih2, const float* __restrict__ bhh2,
                    const float* __restrict__ Wfc, const float* __restrict__ bfc,
                    float* __restrict__ out, unsigned* __restrict__ cnt, int nblk)
{
    constexpr int NHC = NCOLS / 4;      // h-cols per block
    constexpr int NT  = NCOLS / 16;     // N-tiles (2 or 1)
    constexpr int GPR = NHC / 4;        // 8B col-groups per row (2 or 1)
    extern __shared__ bf16 lds[];
    __shared__ __align__(16) bf16 hst[4][32][NHC];   // epilogue staging

    const int tid   = threadIdx.x;
    const int bid   = blockIdx.x;
    const int layer = (bid >> 3) & 1;
    const int slice = (bid & 7) | ((bid >> 4) << 3);
    const int n0h   = slice * NHC;
    const int KLDS  = layer ? K2LDS : K1LDS;
    const int arr_per_line = nblk >> 3;

    // ---- stage weights fp32->bf16 into swizzled LDS (once) ----
    {
        const int cpr = KLDS >> 3;              // 16B chunks per row
        const int total = NCOLS * cpr;
        for (int ci = tid; ci < total; ci += 256) {
            int r = ci / cpr, c = ci - r * cpr;
            int g = r / NHC, j = r - g * NHC;
            int grow = (g << 10) + n0h + j;
            int k0 = c << 3;
            float v[8];
#pragma unroll
            for (int u = 0; u < 8; ++u) {
                int k = k0 + u;
                if (layer == 0)
                    v[u] = (k < I_) ? Wih1[(size_t)grow * I_ + k]
                         : (k < KX_) ? 0.f
                         : (k < KX_ + H_) ? Whh1[(size_t)grow * H_ + (k - KX_)] : 0.f;
                else
                    v[u] = (k < H_) ? Wih2[(size_t)grow * H_ + k]
                                    : Whh2[(size_t)grow * H_ + (k - H_)];
            }
            int cs = (c & ~15) | ((c ^ r) & 15);      // XOR swizzle
            bf16* dst = lds + (size_t)r * KLDS + (cs << 3);
#pragma unroll
            for (int u = 0; u < 8; ++u) dst[u] = (bf16)v[u];
        }
    }
    __syncthreads();

    const int lane = tid & 63;
    const int wv   = tid >> 6;
    const int jj   = lane & (NHC - 1);
    const int quad = lane >> 4;

    float4 bias;
    {
        const float* bi = layer ? bih2 : bih1;
        const float* bh = layer ? bhh2 : bhh1;
        int col = n0h + jj;
        bias.x = bi[col] + bh[col];
        bias.y = bi[col + H_] + bh[col + H_];
        bias.z = bi[col + 2 * H_] + bh[col + 2 * H_];
        bias.w = bi[col + 3 * H_] + bh[col + 3 * H_];
    }

    float creg[4];
    {
        const float* cin = layer ? c2in : c1in;
        if constexpr (NCOLS == 32) {
            int dup = (lane >> 3) & 1;
#pragma unroll
            for (int t = 0; t < 2; ++t)
#pragma unroll
                for (int rp = 0; rp < 2; ++rp) {
                    int r = rp * 2 + dup;
                    int row = wv * 32 + t * 16 + quad * 4 + r;
                    creg[t * 2 + rp] = cin[(size_t)row * H_ + n0h + jj];
                }
        } else {
            int r = (lane >> 2) & 3;
#pragma unroll
            for (int t = 0; t < 2; ++t) {
                int row = wv * 32 + t * 16 + quad * 4 + r;
                creg[t] = cin[(size_t)row * H_ + n0h + jj];
            }
        }
    }

    floatx4 acc[2][NT];

    auto seg = [&](const bf16* A, int ldA, int nks, int ksBase) {
        const int arow = wv * 32 + (lane & 15);
        const bf16* a0 = A + (size_t)arow * ldA + quad * 8;
        const bf16* a1 = a0 + 16 * ldA;
#pragma unroll 4
        for (int ks = 0; ks < nks; ++ks) {
            bf16x8 af0 = *(const bf16x8*)(a0 + ks * 32);
            bf16x8 af1 = *(const bf16x8*)(a1 + ks * 32);
            int c = (ksBase + ks) * 4 + quad;
#pragma unroll
            for (int t = 0; t < NT; ++t) {
                int r = t * 16 + (lane & 15);
                int cs = (c & ~15) | ((c ^ r) & 15);
                bf16x8 bfr = *(const bf16x8*)(lds + (size_t)r * KLDS + (cs << 3));
                acc[0][t] = __builtin_amdgcn_mfma_f32_16x16x32_bf16(af0, bfr, acc[0][t], 0, 0, 0);
                acc[1][t] = __builtin_amdgcn_mfma_f32_16x16x32_bf16(af1, bfr, acc[1][t], 0, 0, 0);
            }
        }
    };

    for (int e = 0; e <= T_; ++e) {
        const bool active = layer == 0 ? (e < T_) : (e >= 1);
        if (active) {
#pragma unroll
            for (int t = 0; t < 2; ++t)
#pragma unroll
                for (int u = 0; u < NT; ++u) acc[t][u] = (floatx4){0.f, 0.f, 0.f, 0.f};

            const bf16* h1r = (e & 1) ? h1b1 : h1b0;         // h1^(e)
            if (layer == 0) {
                const bf16* xt = xb + (size_t)e * B_ * KX_;
                seg(xt, KX_, 5, 0);
                seg(h1r, H_, 32, 5);
            } else {
                const bf16* h2r = (e & 1) ? h2b0 : h2b1;     // h2^(e-1)
                seg(h1r, H_, 32, 0);
                seg(h2r, H_, 32, 32);
            }
            bf16* hw = (layer == 0) ? ((e & 1) ? h1b0 : h1b1)   // h1^(e+1)
                                    : ((e & 1) ? h2b1 : h2b0);  // h2^(e)

            // epilogue: shfl-gather gates, update creg, stage h to LDS
            const int base = lane & 48;
#pragma unroll
            for (int t = 0; t < 2; ++t) {
#pragma unroll
                for (int r = 0; r < 4; ++r) {
                    float vi, vf, vg, vo;
                    if constexpr (NCOLS == 32) {
                        vi = __shfl(acc[t][0][r], base + jj, 64);
                        vf = __shfl(acc[t][0][r], base + 8 + jj, 64);
                        vg = __shfl(acc[t][1][r], base + jj, 64);
                        vo = __shfl(acc[t][1][r], base + 8 + jj, 64);
                    } else {
                        vi = __shfl(acc[t][0][r], base + jj, 64);
                        vf = __shfl(acc[t][0][r], base + 4 + jj, 64);
                        vg = __shfl(acc[t][0][r], base + 8 + jj, 64);
                        vo = __shfl(acc[t][0][r], base + 12 + jj, 64);
                    }
                    bool cond; int slot;
                    if constexpr (NCOLS == 32) {
                        cond = (((lane >> 3) & 1) == (r & 1));
                        slot = t * 2 + (r >> 1);
                    } else {
                        cond = (((lane >> 2) & 3) == r);
                        slot = t;
                    }
                    if (cond) {
                        float cv = creg[slot];
                        float cn = sigmoidf_(vf + bias.y) * cv
                                 + sigmoidf_(vi + bias.x) * tanhf(vg + bias.z);
                        creg[slot] = cn;
                        float hn = sigmoidf_(vo + bias.w) * tanhf(cn);
                        hst[wv][t * 16 + quad * 4 + r][jj] = (bf16)hn;
                    }
                }
            }
            __syncthreads();
            // vectorized 8B relaxed-agent atomic stores (write-through, no fence)
            if (lane < 32 * GPR) {
                int row_l = lane / GPR, cg = lane - row_l * GPR;
                ull v = *(const ull*)&hst[wv][row_l][cg * 4];
                __hip_atomic_store((ull*)(hw + (size_t)(wv * 32 + row_l) * H_ + n0h + cg * 4),
                                   v, __ATOMIC_RELAXED, __HIP_MEMORY_SCOPE_AGENT);
            }
        }

        // ---- two-level barrier: RMW lines (0..7) + broadcast flag line (8) ----
        asm volatile("s_waitcnt vmcnt(0)" ::: "memory");
        __syncthreads();
        const unsigned etag = (unsigned)(e + 1);
        if (bid == 0) {
            // master: arrive, aggregate 8 counters with lanes 0..7, publish flag
            if (tid == 0)
                __hip_atomic_fetch_add(cnt, 1u, __ATOMIC_RELAXED, __HIP_MEMORY_SCOPE_AGENT);
            if (tid < 8) {
                const unsigned tgt = etag * (unsigned)arr_per_line;
                const unsigned* cp = cnt + tid * CSTRIDE;
                while (__hip_atomic_load(cp, __ATOMIC_RELAXED, __HIP_MEMORY_SCOPE_AGENT) < tgt)
                    __builtin_amdgcn_s_sleep(1);
            }
            if (tid == 0)
                __hip_atomic_store(cnt + 8 * CSTRIDE, etag,
                                   __ATOMIC_RELAXED, __HIP_MEMORY_SCOPE_AGENT);
        } else {
            if (tid == 0) {
                __hip_atomic_fetch_add(cnt + (bid & 7) * CSTRIDE, 1u,
                                       __ATOMIC_RELAXED, __HIP_MEMORY_SCOPE_AGENT);
                const unsigned* fp = cnt + 8 * CSTRIDE;
                while (__hip_atomic_load(fp, __ATOMIC_RELAXED, __HIP_MEMORY_SCOPE_AGENT) < etag)
                    __builtin_amdgcn_s_sleep(4);
            }
        }
        __syncthreads();
        // exactly one acquire (cache inv) per wave per epoch
        __builtin_amdgcn_fence(__ATOMIC_ACQUIRE, "agent");
    }

    // ---- fused FC: out = h2^(256) @ Wfc^T + bfc ; h2^(256) is in h2b0 ----
    if (bid < B_) {
        const bf16* h2f = h2b0;
        for (int c = wv; c < C_; c += 4) {
            float a = 0.f;
            for (int k = lane; k < H_; k += 64)
                a += (float)h2f[(size_t)bid * H_ + k] * Wfc[(size_t)c * H_ + k];
#pragma unroll
            for (int off = 32; off; off >>= 1) a += __shfl_down(a, off, 64);
            if (lane == 0) out[bid * C_ + c] = a + bfc[c];
        }
    }
}

extern "C" void kernel_launch(void* const* d_in, const int* in_sizes, int n_in,
                              void* d_out, int out_size, void* d_ws, size_t ws_size,
                              hipStream_t stream)
{
    const float* x    = (const float*)d_in[0];
    const float* h1in = (const float*)d_in[1];
    const float* c1in = (const float*)d_in[2];
    const float* h2in = (const float*)d_in[3];
    const float* c2in = (const float*)d_in[4];
    const float* Wih1 = (const float*)d_in[5];
    const float* Whh1 = (const float*)d_in[6];
    const float* bih1 = (const float*)d_in[7];
    const float* bhh1 = (const float*)d_in[8];
    const float* Wih2 = (const float*)d_in[9];
    const float* Whh2 = (const float*)d_in[10];
    const float* bih2 = (const float*)d_in[11];
    const float* bhh2 = (const float*)d_in[12];
    const float* Wfc  = (const float*)d_in[13];
    const float* bfc  = (const float*)d_in[14];
    float* out = (float*)d_out;

    // ws carve (~11.5 MB)
    char* p = (char*)d_ws;
    bf16* xb = (bf16*)p;    p += (size_t)T_ * B_ * KX_ * 2;
    bf16* h1b0 = (bf16*)p;  p += (size_t)B_ * H_ * 2;
    bf16* h1b1 = (bf16*)p;  p += (size_t)B_ * H_ * 2;
    bf16* h2b0 = (bf16*)p;  p += (size_t)B_ * H_ * 2;
    bf16* h2b1 = (bf16*)p;  p += (size_t)B_ * H_ * 2;
    unsigned* cnt = (unsigned*)p;       // 16 lines x 256B

    const size_t citems = (size_t)T_ * B_ * KX_ + 2 * (size_t)B_ * H_ + NLINES * CSTRIDE;
    convert_all<<<(int)((citems + 255) / 256), 256, 0, stream>>>(
        x, h1in, h2in, xb, h1b0, h2b0, cnt);

    int nblk32 = 256, nblk16 = 512;
    void* args32[] = { &xb, &h1b0, &h1b1, &h2b0, &h2b1, (void*)&c1in, (void*)&c2in,
                       (void*)&Wih1, (void*)&Whh1, (void*)&bih1, (void*)&bhh1,
                       (void*)&Wih2, (void*)&Whh2, (void*)&bih2, (void*)&bhh2,
                       (void*)&Wfc, (void*)&bfc, &out, &cnt, &nblk32 };
    void* args16[] = { &xb, &h1b0, &h1b1, &h2b0, &h2b1, (void*)&c1in, (void*)&c2in,
                       (void*)&Wih1, (void*)&Whh1, (void*)&bih1, (void*)&bhh1,
                       (void*)&Wih2, (void*)&Whh2, (void*)&bih2, (void*)&bhh2,
                       (void*)&Wfc, (void*)&bfc, &out, &cnt, &nblk16 };

    (void)hipFuncSetAttribute((const void*)rnn_persistent<32>,
                              hipFuncAttributeMaxDynamicSharedMemorySize, 131072);
    hipError_t err = hipLaunchCooperativeKernel((const void*)rnn_persistent<32>,
                                                dim3(256), dim3(256), args32,
                                                131072u, stream);
    if (err != hipSuccess) {
        (void)hipGetLastError();
        (void)hipFuncSetAttribute((const void*)rnn_persistent<16>,
                                  hipFuncAttributeMaxDynamicSharedMemorySize, 65536);
        (void)hipLaunchCooperativeKernel((const void*)rnn_persistent<16>,
                                         dim3(512), dim3(256), args16,
                                         65536u, stream);
    }
}

// Round 6
// 5616.771 us; speedup vs baseline: 2.4569x; 1.5022x over previous
//
#include <hip/hip_runtime.h>
#include <math.h>

// stacked_rnn R6: persistent cooperative kernel, weights LDS-resident.
// = R4 (proven-correct protocol: relaxed-atomic h stores + two-level barrier +
//   per-epoch agent-acquire fence) with two changes:
//   (1) fence executed by wave 0 only (256 not 1024 cache-inv walks/epoch)
//   (2) seg loops chunked: 32 A-loads batched to registers before consumption
//       (hides post-invalidate L2-miss latency; ~190 VGPR, 1 wave/SIMD anyway)

typedef __bf16 bf16;
typedef __bf16 bf16x8 __attribute__((ext_vector_type(8)));
typedef float floatx4 __attribute__((ext_vector_type(4)));
typedef unsigned long long ull;

#define B_   128
#define T_   256
#define H_   1024
#define I_   150
#define KX_  160
#define C_   60
#define K1LDS 1280   // layer-1 LDS row width in elems
#define K2LDS 2048   // layer-2 LDS row width
#define NLINES 16    // counter lines
#define CSTRIDE 64   // uints between lines (256B)

template<int N> struct IC { static constexpr int value = N; };

__device__ __forceinline__ float sigmoidf_(float x) { return 1.f / (1.f + expf(-x)); }

// ---------------- conversion / init kernel ----------------
__global__ __launch_bounds__(256)
void convert_all(const float* __restrict__ x,
                 const float* __restrict__ h1in, const float* __restrict__ h2in,
                 bf16* __restrict__ xb, bf16* __restrict__ h1b0, bf16* __restrict__ h2b0,
                 unsigned* __restrict__ cnt)
{
    const size_t nXB = (size_t)T_ * B_ * KX_;   // 5242880
    const size_t nHC = (size_t)B_ * H_;         // 131072
    size_t idx = (size_t)blockIdx.x * 256 + threadIdx.x;

    if (idx < nXB) {                            // x [B][T][150] -> xb [T][B][160]
        size_t t = idx / (B_ * KX_);
        size_t r = idx - t * (B_ * KX_);
        size_t b = r / KX_, k = r - b * KX_;
        xb[idx] = (k < I_) ? (bf16)x[(b * T_ + t) * I_ + k] : (bf16)0.f;
        return;
    }
    idx -= nXB;
    if (idx < nHC) { h1b0[idx] = (bf16)h1in[idx]; return; }
    idx -= nHC;
    if (idx < nHC) { h2b0[idx] = (bf16)h2in[idx]; return; }
    idx -= nHC;
    if (idx < NLINES * CSTRIDE) cnt[idx] = 0u;
}

// ---------------- persistent LSTM kernel ----------------
// NCOLS=32 -> 256 blocks/128KiB LDS; NCOLS=16 -> 512 blocks/64KiB LDS.
// layer = (bid>>3)&1, slice = (bid&7)|((bid>>4)<<3).
// cnt lines 0..7: arrival counters by (bid&7). line 8: epoch broadcast flag.
template<int NCOLS>
__global__ __launch_bounds__(256, 1)
void rnn_persistent(const bf16* __restrict__ xb,
                    bf16* __restrict__ h1b0, bf16* __restrict__ h1b1,
                    bf16* __restrict__ h2b0, bf16* __restrict__ h2b1,
                    const float* __restrict__ c1in, const float* __restrict__ c2in,
                    const float* __restrict__ Wih1, const float* __restrict__ Whh1,
                    const float* __restrict__ bih1, const float* __restrict__ bhh1,
                    const float* __restrict__ Wih2, const float* __restrict__ Whh2,
                    const float* __restrict__ bih2, const float* __restrict__ bhh2,
                    const float* __restrict__ Wfc, const float* __restrict__ bfc,
                    float* __restrict__ out, unsigned* __restrict__ cnt, int nblk)
{
    constexpr int NHC = NCOLS / 4;      // h-cols per block
    constexpr int NT  = NCOLS / 16;     // N-tiles (2 or 1)
    constexpr int GPR = NHC / 4;        // 8B col-groups per row (2 or 1)
    extern __shared__ bf16 lds[];
    __shared__ __align__(16) bf16 hst[4][32][NHC];   // epilogue staging

    const int tid   = threadIdx.x;
    const int bid   = blockIdx.x;
    const int layer = (bid >> 3) & 1;
    const int slice = (bid & 7) | ((bid >> 4) << 3);
    const int n0h   = slice * NHC;
    const int KLDS  = layer ? K2LDS : K1LDS;
    const int arr_per_line = nblk >> 3;

    // ---- stage weights fp32->bf16 into swizzled LDS (once) ----
    {
        const int cpr = KLDS >> 3;              // 16B chunks per row
        const int total = NCOLS * cpr;
        for (int ci = tid; ci < total; ci += 256) {
            int r = ci / cpr, c = ci - r * cpr;
            int g = r / NHC, j = r - g * NHC;
            int grow = (g << 10) + n0h + j;
            int k0 = c << 3;
            float v[8];
#pragma unroll
            for (int u = 0; u < 8; ++u) {
                int k = k0 + u;
                if (layer == 0)
                    v[u] = (k < I_) ? Wih1[(size_t)grow * I_ + k]
                         : (k < KX_) ? 0.f
                         : (k < KX_ + H_) ? Whh1[(size_t)grow * H_ + (k - KX_)] : 0.f;
                else
                    v[u] = (k < H_) ? Wih2[(size_t)grow * H_ + k]
                                    : Whh2[(size_t)grow * H_ + (k - H_)];
            }
            int cs = (c & ~15) | ((c ^ r) & 15);      // XOR swizzle
            bf16* dst = lds + (size_t)r * KLDS + (cs << 3);
#pragma unroll
            for (int u = 0; u < 8; ++u) dst[u] = (bf16)v[u];
        }
    }
    __syncthreads();

    const int lane = tid & 63;
    const int wv   = tid >> 6;
    const int jj   = lane & (NHC - 1);
    const int quad = lane >> 4;

    float4 bias;
    {
        const float* bi = layer ? bih2 : bih1;
        const float* bh = layer ? bhh2 : bhh1;
        int col = n0h + jj;
        bias.x = bi[col] + bh[col];
        bias.y = bi[col + H_] + bh[col + H_];
        bias.z = bi[col + 2 * H_] + bh[col + 2 * H_];
        bias.w = bi[col + 3 * H_] + bh[col + 3 * H_];
    }

    float creg[4];
    {
        const float* cin = layer ? c2in : c1in;
        if constexpr (NCOLS == 32) {
            int dup = (lane >> 3) & 1;
#pragma unroll
            for (int t = 0; t < 2; ++t)
#pragma unroll
                for (int rp = 0; rp < 2; ++rp) {
                    int r = rp * 2 + dup;
                    int row = wv * 32 + t * 16 + quad * 4 + r;
                    creg[t * 2 + rp] = cin[(size_t)row * H_ + n0h + jj];
                }
        } else {
            int r = (lane >> 2) & 3;
#pragma unroll
            for (int t = 0; t < 2; ++t) {
                int row = wv * 32 + t * 16 + quad * 4 + r;
                creg[t] = cin[(size_t)row * H_ + n0h + jj];
            }
        }
    }

    floatx4 acc[2][NT];

    // chunked K-segment: batch up to 16 k-steps (32 global loads) into
    // registers BEFORE consuming -> post-invalidate misses overlap.
    auto seg = [&](const bf16* A, int ldA, auto nksC, int ksBase) {
        constexpr int NKS = decltype(nksC)::value;
        constexpr int CH  = NKS < 16 ? NKS : 16;
        const int arow = wv * 32 + (lane & 15);
        const bf16* a0 = A + (size_t)arow * ldA + quad * 8;
        const bf16* a1 = a0 + 16 * ldA;
        for (int blk = 0; blk < NKS; blk += CH) {
            bf16x8 a0r[CH], a1r[CH];
#pragma unroll
            for (int i = 0; i < CH; ++i) {
                a0r[i] = *(const bf16x8*)(a0 + (blk + i) * 32);
                a1r[i] = *(const bf16x8*)(a1 + (blk + i) * 32);
            }
#pragma unroll
            for (int i = 0; i < CH; ++i) {
                int c = (ksBase + blk + i) * 4 + quad;
#pragma unroll
                for (int t = 0; t < NT; ++t) {
                    int r = t * 16 + (lane & 15);
                    int cs = (c & ~15) | ((c ^ r) & 15);
                    bf16x8 bfr = *(const bf16x8*)(lds + (size_t)r * KLDS + (cs << 3));
                    acc[0][t] = __builtin_amdgcn_mfma_f32_16x16x32_bf16(a0r[i], bfr, acc[0][t], 0, 0, 0);
                    acc[1][t] = __builtin_amdgcn_mfma_f32_16x16x32_bf16(a1r[i], bfr, acc[1][t], 0, 0, 0);
                }
            }
        }
    };

    for (int e = 0; e <= T_; ++e) {
        const bool active = layer == 0 ? (e < T_) : (e >= 1);
        if (active) {
#pragma unroll
            for (int t = 0; t < 2; ++t)
#pragma unroll
                for (int u = 0; u < NT; ++u) acc[t][u] = (floatx4){0.f, 0.f, 0.f, 0.f};

            const bf16* h1r = (e & 1) ? h1b1 : h1b0;         // h1^(e)
            if (layer == 0) {
                const bf16* xt = xb + (size_t)e * B_ * KX_;
                seg(xt, KX_, IC<5>{}, 0);
                seg(h1r, H_, IC<32>{}, 5);
            } else {
                const bf16* h2r = (e & 1) ? h2b0 : h2b1;     // h2^(e-1)
                seg(h1r, H_, IC<32>{}, 0);
                seg(h2r, H_, IC<32>{}, 32);
            }
            bf16* hw = (layer == 0) ? ((e & 1) ? h1b0 : h1b1)   // h1^(e+1)
                                    : ((e & 1) ? h2b1 : h2b0);  // h2^(e)

            // epilogue: shfl-gather gates, update creg, stage h to LDS
            const int base = lane & 48;
#pragma unroll
            for (int t = 0; t < 2; ++t) {
#pragma unroll
                for (int r = 0; r < 4; ++r) {
                    float vi, vf, vg, vo;
                    if constexpr (NCOLS == 32) {
                        vi = __shfl(acc[t][0][r], base + jj, 64);
                        vf = __shfl(acc[t][0][r], base + 8 + jj, 64);
                        vg = __shfl(acc[t][1][r], base + jj, 64);
                        vo = __shfl(acc[t][1][r], base + 8 + jj, 64);
                    } else {
                        vi = __shfl(acc[t][0][r], base + jj, 64);
                        vf = __shfl(acc[t][0][r], base + 4 + jj, 64);
                        vg = __shfl(acc[t][0][r], base + 8 + jj, 64);
                        vo = __shfl(acc[t][0][r], base + 12 + jj, 64);
                    }
                    bool cond; int slot;
                    if constexpr (NCOLS == 32) {
                        cond = (((lane >> 3) & 1) == (r & 1));
                        slot = t * 2 + (r >> 1);
                    } else {
                        cond = (((lane >> 2) & 3) == r);
                        slot = t;
                    }
                    if (cond) {
                        float cv = creg[slot];
                        float cn = sigmoidf_(vf + bias.y) * cv
                                 + sigmoidf_(vi + bias.x) * tanhf(vg + bias.z);
                        creg[slot] = cn;
                        float hn = sigmoidf_(vo + bias.w) * tanhf(cn);
                        hst[wv][t * 16 + quad * 4 + r][jj] = (bf16)hn;
                    }
                }
            }
            __syncthreads();
            // vectorized 8B relaxed-agent atomic stores (LLC write-through)
            if (lane < 32 * GPR) {
                int row_l = lane / GPR, cg = lane - row_l * GPR;
                ull v = *(const ull*)&hst[wv][row_l][cg * 4];
                __hip_atomic_store((ull*)(hw + (size_t)(wv * 32 + row_l) * H_ + n0h + cg * 4),
                                   v, __ATOMIC_RELAXED, __HIP_MEMORY_SCOPE_AGENT);
            }
        }

        // ---- two-level barrier: RMW lines (0..7) + broadcast flag line (8) ----
        asm volatile("s_waitcnt vmcnt(0)" ::: "memory");
        __syncthreads();
        const unsigned etag = (unsigned)(e + 1);
        if (bid == 0) {
            if (tid == 0)
                __hip_atomic_fetch_add(cnt, 1u, __ATOMIC_RELAXED, __HIP_MEMORY_SCOPE_AGENT);
            if (tid < 8) {
                const unsigned tgt = etag * (unsigned)arr_per_line;
                const unsigned* cp = cnt + tid * CSTRIDE;
                while (__hip_atomic_load(cp, __ATOMIC_RELAXED, __HIP_MEMORY_SCOPE_AGENT) < tgt)
                    __builtin_amdgcn_s_sleep(1);
            }
            if (tid == 0)
                __hip_atomic_store(cnt + 8 * CSTRIDE, etag,
                                   __ATOMIC_RELAXED, __HIP_MEMORY_SCOPE_AGENT);
        } else {
            if (tid == 0) {
                __hip_atomic_fetch_add(cnt + (bid & 7) * CSTRIDE, 1u,
                                       __ATOMIC_RELAXED, __HIP_MEMORY_SCOPE_AGENT);
                const unsigned* fp = cnt + 8 * CSTRIDE;
                while (__hip_atomic_load(fp, __ATOMIC_RELAXED, __HIP_MEMORY_SCOPE_AGENT) < etag)
                    __builtin_amdgcn_s_sleep(1);
            }
        }
        __syncthreads();
        // acquire (cache inv) by wave 0 only: invalidates this CU's L1 + XCD L2
        if (tid < 64)
            __builtin_amdgcn_fence(__ATOMIC_ACQUIRE, "agent");
        __syncthreads();
    }

    // ---- fused FC: out = h2^(256) @ Wfc^T + bfc ; h2^(256) is in h2b0 ----
    if (bid < B_) {
        const bf16* h2f = h2b0;
        for (int c = wv; c < C_; c += 4) {
            float a = 0.f;
            for (int k = lane; k < H_; k += 64)
                a += (float)h2f[(size_t)bid * H_ + k] * Wfc[(size_t)c * H_ + k];
#pragma unroll
            for (int off = 32; off; off >>= 1) a += __shfl_down(a, off, 64);
            if (lane == 0) out[bid * C_ + c] = a + bfc[c];
        }
    }
}

extern "C" void kernel_launch(void* const* d_in, const int* in_sizes, int n_in,
                              void* d_out, int out_size, void* d_ws, size_t ws_size,
                              hipStream_t stream)
{
    const float* x    = (const float*)d_in[0];
    const float* h1in = (const float*)d_in[1];
    const float* c1in = (const float*)d_in[2];
    const float* h2in = (const float*)d_in[3];
    const float* c2in = (const float*)d_in[4];
    const float* Wih1 = (const float*)d_in[5];
    const float* Whh1 = (const float*)d_in[6];
    const float* bih1 = (const float*)d_in[7];
    const float* bhh1 = (const float*)d_in[8];
    const float* Wih2 = (const float*)d_in[9];
    const float* Whh2 = (const float*)d_in[10];
    const float* bih2 = (const float*)d_in[11];
    const float* bhh2 = (const float*)d_in[12];
    const float* Wfc  = (const float*)d_in[13];
    const float* bfc  = (const float*)d_in[14];
    float* out = (float*)d_out;

    // ws carve (~11.5 MB)
    char* p = (char*)d_ws;
    bf16* xb = (bf16*)p;    p += (size_t)T_ * B_ * KX_ * 2;
    bf16* h1b0 = (bf16*)p;  p += (size_t)B_ * H_ * 2;
    bf16* h1b1 = (bf16*)p;  p += (size_t)B_ * H_ * 2;
    bf16* h2b0 = (bf16*)p;  p += (size_t)B_ * H_ * 2;
    bf16* h2b1 = (bf16*)p;  p += (size_t)B_ * H_ * 2;
    unsigned* cnt = (unsigned*)p;       // 16 lines x 256B

    const size_t citems = (size_t)T_ * B_ * KX_ + 2 * (size_t)B_ * H_ + NLINES * CSTRIDE;
    convert_all<<<(int)((citems + 255) / 256), 256, 0, stream>>>(
        x, h1in, h2in, xb, h1b0, h2b0, cnt);

    int nblk32 = 256, nblk16 = 512;
    void* args32[] = { &xb, &h1b0, &h1b1, &h2b0, &h2b1, (void*)&c1in, (void*)&c2in,
                       (void*)&Wih1, (void*)&Whh1, (void*)&bih1, (void*)&bhh1,
                       (void*)&Wih2, (void*)&Whh2, (void*)&bih2, (void*)&bhh2,
                       (void*)&Wfc, (void*)&bfc, &out, &cnt, &nblk32 };
    void* args16[] = { &xb, &h1b0, &h1b1, &h2b0, &h2b1, (void*)&c1in, (void*)&c2in,
                       (void*)&Wih1, (void*)&Whh1, (void*)&bih1, (void*)&bhh1,
                       (void*)&Wih2, (void*)&Whh2, (void*)&bih2, (void*)&bhh2,
                       (void*)&Wfc, (void*)&bfc, &out, &cnt, &nblk16 };

    (void)hipFuncSetAttribute((const void*)rnn_persistent<32>,
                              hipFuncAttributeMaxDynamicSharedMemorySize, 131072);
    hipError_t err = hipLaunchCooperativeKernel((const void*)rnn_persistent<32>,
                                                dim3(256), dim3(256), args32,
                                                131072u, stream);
    if (err != hipSuccess) {
        (void)hipGetLastError();
        (void)hipFuncSetAttribute((const void*)rnn_persistent<16>,
                                  hipFuncAttributeMaxDynamicSharedMemorySize, 65536);
        (void)hipLaunchCooperativeKernel((const void*)rnn_persistent<16>,
                                         dim3(512), dim3(256), args16,
                                         65536u, stream);
    }
}